// Round 2
// baseline (86.418 us; speedup 1.0000x reference)
//
#include <hip/hip_runtime.h>
#include <hip/hip_bf16.h>
#include <math.h>

#define PI_F 3.14159265358979323846f
#define EPS_F 1e-6f

// Shapes (fixed by the reference): B=1, V=2, W=32, H=16, M=512. All f32 I/O.
//
// One wave (64 lanes) per (n,v) pair. Lanes split the M=512 light samples
// (8 each, stride 64 -> coalesced env_vis reads, conflict-free LDS reads).
// Per-m tables (light dir + env_map*solid_angle) built once per block in LDS.
// The reference's bilinear grid-sample degenerates to an exact pixel lookup
// (sample coords land on integer pixel centers): Li[m=y*32+x, c] = env_map[x,y,c].

__global__ __launch_bounds__(256) void hdr_render_kernel(
    const float* __restrict__ normals,    // (N,3)
    const float* __restrict__ albedo,     // (N,3)
    const float* __restrict__ metallic,   // (N,1)
    const float* __restrict__ smooth,     // (N,1)
    const float* __restrict__ vdirs,      // (N,2,3)
    const float* __restrict__ env_vis,    // (N,512)
    const float* __restrict__ env_map,    // (32,16,3)
    float* __restrict__ out,              // (N,2,3)
    int n_pairs)
{
    __shared__ float s_lx[512], s_ly[512], s_lz[512];
    __shared__ float s_L0[512], s_L1[512], s_L2[512];

    const int tid = threadIdx.x;

    // ---- build per-light-sample tables (identical in every block; cheap) ----
    for (int m = tid; m < 512; m += 256) {
        const int x = m & 31;        // fast (u) axis, W=32
        const int y = m >> 5;        // slow (v) axis, H=16
        const float u  = (x + 0.5f) * (1.0f / 32.0f);
        const float vv = (y + 0.5f) * (1.0f / 16.0f);
        const float phi   = u * (2.0f * PI_F) + 0.5f * PI_F;
        const float theta = vv * PI_F;
        float st, ct, sp, cp;
        sincosf(theta, &st, &ct);
        sincosf(phi,   &sp, &cp);
        s_lx[m] = st * cp;
        s_ly[m] = ct;
        s_lz[m] = -st * sp;
        const float sa = st * (PI_F / 16.0f) * (2.0f * PI_F / 32.0f);
        const int base = (x * 16 + y) * 3;
        s_L0[m] = env_map[base + 0] * sa;
        s_L1[m] = env_map[base + 1] * sa;
        s_L2[m] = env_map[base + 2] * sa;
    }
    __syncthreads();

    const int lane = tid & 63;
    const int wave = tid >> 6;
    const int pair = blockIdx.x * 4 + wave;
    if (pair >= n_pairs) return;
    const int n = pair >> 1;   // point index; view index = pair & 1 (folded in)

    // ---- per-pair scalars (computed redundantly by all lanes) ----
    float nx = normals[n * 3 + 0];
    float ny = normals[n * 3 + 1];
    float nz = normals[n * 3 + 2];
    {
        const float len = sqrtf(nx * nx + ny * ny + nz * nz);
        const float inv = 1.0f / fmaxf(len, 1e-12f);
        nx *= inv; ny *= inv; nz *= inv;
    }
    float vx = vdirs[pair * 3 + 0];
    float vy = vdirs[pair * 3 + 1];
    float vz = vdirs[pair * 3 + 2];
    {
        const float len = sqrtf(vx * vx + vy * vy + vz * vz);
        const float inv = 1.0f / fmaxf(len, 1e-12f);
        vx *= inv; vy *= inv; vz *= inv;
    }
    const float alb0 = albedo[n * 3 + 0];
    const float alb1 = albedo[n * 3 + 1];
    const float alb2 = albedo[n * 3 + 2];
    const float met  = metallic[n];
    const float sm   = smooth[n];

    const float NdotV  = fmaxf(nx * vx + ny * vy + nz * vz, EPS_F);
    const float rough  = 1.0f - sm;
    const float alpha  = rough * rough;
    const float alpha2 = alpha * alpha;
    const float k      = 0.5f * alpha;
    const float gv     = NdotV / (NdotV * (1.0f - k) + k + EPS_F);

    const float f00 = 0.04f + (alb0 - 0.04f) * met;
    const float f01 = 0.04f + (alb1 - 0.04f) * met;
    const float f02 = 0.04f + (alb2 - 0.04f) * met;
    const float db0 = (1.0f - met) * alb0 * (1.0f / PI_F);
    const float db1 = (1.0f - met) * alb1 * (1.0f / PI_F);
    const float db2 = (1.0f - met) * alb2 * (1.0f / PI_F);

    const float* __restrict__ visrow = env_vis + (size_t)n * 512;

    float acc0 = 0.0f, acc1 = 0.0f, acc2 = 0.0f;

    #pragma unroll
    for (int i = 0; i < 8; ++i) {
        const int m = i * 64 + lane;
        const float lx = s_lx[m];
        const float ly = s_ly[m];
        const float lz = s_lz[m];
        const float vis = visrow[m];

        // half vector (reference: normalize with max(|h|,1e-12))
        float hx = vx + lx, hy = vy + ly, hz = vz + lz;
        const float hlen = sqrtf(hx * hx + hy * hy + hz * hz);
        const float hinv = 1.0f / fmaxf(hlen, 1e-12f);
        hx *= hinv; hy *= hinv; hz *= hinv;

        const float NdotL = fmaxf(nx * lx + ny * ly + nz * lz, EPS_F);
        const float NdotH = fmaxf(nx * hx + ny * hy + nz * hz, 0.0f);
        const float VdotH = fmaxf(lx * hx + ly * hy + lz * hz, 0.0f); // ref uses l.h

        // Fresnel: p5 = (1 - clip(VdotH,0,1))^5
        const float p  = 1.0f - fminf(VdotH, 1.0f);
        const float p2 = p * p;
        const float p5 = p2 * p2 * p;

        // GGX D
        const float dn = NdotH * NdotH * (alpha2 - 1.0f) + 1.0f;
        const float D  = alpha2 / (PI_F * dn * dn + EPS_F);

        // Smith G (gv precomputed)
        const float gl = NdotL / (NdotL * (1.0f - k) + k + EPS_F);

        const float sfac = D * gv * gl / (4.0f * NdotV * NdotL + EPS_F);
        const float w    = vis * NdotL;

        const float Fr0 = f00 + (1.0f - f00) * p5;
        const float Fr1 = f01 + (1.0f - f01) * p5;
        const float Fr2 = f02 + (1.0f - f02) * p5;

        acc0 += (db0 * (1.0f - Fr0) + Fr0 * sfac) * s_L0[m] * w;
        acc1 += (db1 * (1.0f - Fr1) + Fr1 * sfac) * s_L1[m] * w;
        acc2 += (db2 * (1.0f - Fr2) + Fr2 * sfac) * s_L2[m] * w;
    }

    // ---- wave64 butterfly reduction ----
    #pragma unroll
    for (int off = 32; off >= 1; off >>= 1) {
        acc0 += __shfl_down(acc0, off, 64);
        acc1 += __shfl_down(acc1, off, 64);
        acc2 += __shfl_down(acc2, off, 64);
    }

    if (lane == 0) {
        out[pair * 3 + 0] = acc0;
        out[pair * 3 + 1] = acc1;
        out[pair * 3 + 2] = acc2;
    }
}

extern "C" void kernel_launch(void* const* d_in, const int* in_sizes, int n_in,
                              void* d_out, int out_size, void* d_ws, size_t ws_size,
                              hipStream_t stream) {
    const float* normals  = (const float*)d_in[0];
    const float* albedo   = (const float*)d_in[1];
    const float* metallic = (const float*)d_in[2];
    const float* smooth   = (const float*)d_in[3];
    const float* vdirs    = (const float*)d_in[4];
    const float* env_vis  = (const float*)d_in[5];
    const float* env_map  = (const float*)d_in[6];
    float* out = (float*)d_out;

    const int N = in_sizes[0] / 3;        // 4096
    const int n_pairs = N * 2;            // 8192 (n,v) pairs
    const int blocks = (n_pairs + 3) / 4; // 4 waves (pairs) per 256-thread block

    hdr_render_kernel<<<blocks, 256, 0, stream>>>(
        normals, albedo, metallic, smooth, vdirs, env_vis, env_map, out, n_pairs);
}

// Round 3
// 77.721 us; speedup vs baseline: 1.1119x; 1.1119x over previous
//
#include <hip/hip_runtime.h>
#include <math.h>

#define PI_F 3.14159265358979323846f
#define EPS_F 1e-6f

// B=1, V=2, W=32, H=16, M=512, f32 I/O.
//
// One wave (64 lanes) per POINT; each lane handles 8 consecutive light
// samples (m = lane*8+i, two float4 vis loads) and computes BOTH views,
// sharing NdotL / glden / vis / L*vis*NdotL across views. LDS tables are
// stored swizzled (sigma(m) = (m&7)*64 + (m>>3)) so reads at i*64+lane are
// bank-conflict-free. Per-sample divides merged into a single v_rcp_f32;
// h never normalized (rsq of |h|^2 folded into the two dot products).
// Bilinear grid-sample degenerates to exact pixel lookup: Li[m]=env_map[x,y].

__global__ __launch_bounds__(256) void hdr_render_kernel(
    const float* __restrict__ normals,    // (N,3)
    const float* __restrict__ albedo,     // (N,3)
    const float* __restrict__ metallic,   // (N,1)
    const float* __restrict__ smooth,     // (N,1)
    const float* __restrict__ vdirs,      // (N,2,3)
    const float* __restrict__ env_vis,    // (N,512)
    const float* __restrict__ env_map,    // (32,16,3)
    float* __restrict__ out,              // (N,2,3)
    int N)
{
    __shared__ float s_lx[512], s_ly[512], s_lz[512];
    __shared__ float s_L0[512], s_L1[512], s_L2[512];

    const int tid = threadIdx.x;

    // ---- per-light-sample tables (swizzled storage) ----
    for (int m = tid; m < 512; m += 256) {
        const int x = m & 31;        // u axis, W=32
        const int y = m >> 5;        // v axis, H=16
        const float u  = (x + 0.5f) * (1.0f / 32.0f);
        const float vv = (y + 0.5f) * (1.0f / 16.0f);
        const float phi   = u * (2.0f * PI_F) + 0.5f * PI_F;
        const float theta = vv * PI_F;
        float st, ct, sp, cp;
        sincosf(theta, &st, &ct);
        sincosf(phi,   &sp, &cp);
        const float sa = st * (PI_F / 16.0f) * (2.0f * PI_F / 32.0f);
        const int base = (x * 16 + y) * 3;
        const int sw = (m & 7) * 64 + (m >> 3);   // sigma(m)
        s_lx[sw] = st * cp;
        s_ly[sw] = ct;
        s_lz[sw] = -st * sp;
        s_L0[sw] = env_map[base + 0] * sa;
        s_L1[sw] = env_map[base + 1] * sa;
        s_L2[sw] = env_map[base + 2] * sa;
    }
    __syncthreads();

    const int lane = tid & 63;
    const int wave = tid >> 6;
    const int n = blockIdx.x * 4 + wave;
    if (n >= N) return;

    // ---- per-point scalars ----
    float nx = normals[n * 3 + 0];
    float ny = normals[n * 3 + 1];
    float nz = normals[n * 3 + 2];
    {
        const float inv = 1.0f / fmaxf(sqrtf(nx*nx + ny*ny + nz*nz), 1e-12f);
        nx *= inv; ny *= inv; nz *= inv;
    }
    float vx0 = vdirs[n * 6 + 0], vy0 = vdirs[n * 6 + 1], vz0 = vdirs[n * 6 + 2];
    float vx1 = vdirs[n * 6 + 3], vy1 = vdirs[n * 6 + 4], vz1 = vdirs[n * 6 + 5];
    {
        const float inv = 1.0f / fmaxf(sqrtf(vx0*vx0 + vy0*vy0 + vz0*vz0), 1e-12f);
        vx0 *= inv; vy0 *= inv; vz0 *= inv;
    }
    {
        const float inv = 1.0f / fmaxf(sqrtf(vx1*vx1 + vy1*vy1 + vz1*vz1), 1e-12f);
        vx1 *= inv; vy1 *= inv; vz1 *= inv;
    }
    const float alb0 = albedo[n * 3 + 0];
    const float alb1 = albedo[n * 3 + 1];
    const float alb2 = albedo[n * 3 + 2];
    const float met  = metallic[n];
    const float sm   = smooth[n];

    const float rough  = 1.0f - sm;
    const float alpha  = rough * rough;
    const float alpha2 = alpha * alpha;
    const float a2m1   = alpha2 - 1.0f;
    const float k      = 0.5f * alpha;
    const float omk    = 1.0f - k;
    const float kpe    = k + EPS_F;

    const float NdotV0 = fmaxf(nx*vx0 + ny*vy0 + nz*vz0, EPS_F);
    const float NdotV1 = fmaxf(nx*vx1 + ny*vy1 + nz*vz1, EPS_F);
    const float gv0 = NdotV0 / (NdotV0 * omk + kpe);
    const float gv1 = NdotV1 / (NdotV1 * omk + kpe);
    const float c1v0 = alpha2 * gv0;       // folded into sfac
    const float c1v1 = alpha2 * gv1;
    const float fNV0 = 4.0f * NdotV0;
    const float fNV1 = 4.0f * NdotV1;

    const float f00 = 0.04f + (alb0 - 0.04f) * met;
    const float f01 = 0.04f + (alb1 - 0.04f) * met;
    const float f02 = 0.04f + (alb2 - 0.04f) * met;
    const float omf00 = 1.0f - f00, omf01 = 1.0f - f01, omf02 = 1.0f - f02;
    const float db0 = (1.0f - met) * alb0 * (1.0f / PI_F);
    const float db1 = (1.0f - met) * alb1 * (1.0f / PI_F);
    const float db2 = (1.0f - met) * alb2 * (1.0f / PI_F);

    // ---- vis: 8 samples per lane, two float4 loads ----
    const float* __restrict__ visrow = env_vis + (size_t)n * 512 + lane * 8;
    const float4 vA = *(const float4*)(visrow);
    const float4 vB = *(const float4*)(visrow + 4);
    const float vis[8] = { vA.x, vA.y, vA.z, vA.w, vB.x, vB.y, vB.z, vB.w };

    float a00 = 0.f, a01 = 0.f, a02 = 0.f;   // view 0 rgb
    float a10 = 0.f, a11 = 0.f, a12 = 0.f;   // view 1 rgb

    #pragma unroll
    for (int i = 0; i < 8; ++i) {
        const int idx = i * 64 + lane;        // sigma(lane*8+i)
        const float lx = s_lx[idx];
        const float ly = s_ly[idx];
        const float lz = s_lz[idx];

        const float NdotL = fmaxf(fmaf(nx, lx, fmaf(ny, ly, nz * lz)), EPS_F);
        const float glden = fmaf(NdotL, omk, kpe);
        const float w  = vis[i] * NdotL;
        const float t0 = s_L0[idx] * w;
        const float t1 = s_L1[idx] * w;
        const float t2 = s_L2[idx] * w;

        // ---- view 0 ----
        {
            const float hx = vx0 + lx, hy = vy0 + ly, hz = vz0 + lz;
            const float h2 = fmaf(hx, hx, fmaf(hy, hy, hz * hz));
            const float hinv = __builtin_amdgcn_rsqf(fmaxf(h2, 1e-24f));
            const float nh = fmaf(nx, hx, fmaf(ny, hy, nz * hz));
            const float lh = fmaf(lx, hx, fmaf(ly, hy, lz * hz));
            const float NdotH = fmaxf(nh * hinv, 0.0f);
            const float VdotH = fmaxf(lh * hinv, 0.0f);
            const float p  = 1.0f - fminf(VdotH, 1.0f);
            const float p2 = p * p;
            const float p5 = p2 * p2 * p;
            const float dn   = fmaf(NdotH * NdotH, a2m1, 1.0f);
            const float Dden = fmaf(PI_F * dn, dn, EPS_F);
            const float sden = fmaf(fNV0, NdotL, EPS_F);
            const float sfac = c1v0 * NdotL * __builtin_amdgcn_rcpf(Dden * glden * sden);
            const float Fr0 = fmaf(omf00, p5, f00);
            const float Fr1 = fmaf(omf01, p5, f01);
            const float Fr2 = fmaf(omf02, p5, f02);
            a00 = fmaf(fmaf(Fr0, sfac, db0 * (1.0f - Fr0)), t0, a00);
            a01 = fmaf(fmaf(Fr1, sfac, db1 * (1.0f - Fr1)), t1, a01);
            a02 = fmaf(fmaf(Fr2, sfac, db2 * (1.0f - Fr2)), t2, a02);
        }
        // ---- view 1 ----
        {
            const float hx = vx1 + lx, hy = vy1 + ly, hz = vz1 + lz;
            const float h2 = fmaf(hx, hx, fmaf(hy, hy, hz * hz));
            const float hinv = __builtin_amdgcn_rsqf(fmaxf(h2, 1e-24f));
            const float nh = fmaf(nx, hx, fmaf(ny, hy, nz * hz));
            const float lh = fmaf(lx, hx, fmaf(ly, hy, lz * hz));
            const float NdotH = fmaxf(nh * hinv, 0.0f);
            const float VdotH = fmaxf(lh * hinv, 0.0f);
            const float p  = 1.0f - fminf(VdotH, 1.0f);
            const float p2 = p * p;
            const float p5 = p2 * p2 * p;
            const float dn   = fmaf(NdotH * NdotH, a2m1, 1.0f);
            const float Dden = fmaf(PI_F * dn, dn, EPS_F);
            const float sden = fmaf(fNV1, NdotL, EPS_F);
            const float sfac = c1v1 * NdotL * __builtin_amdgcn_rcpf(Dden * glden * sden);
            const float Fr0 = fmaf(omf00, p5, f00);
            const float Fr1 = fmaf(omf01, p5, f01);
            const float Fr2 = fmaf(omf02, p5, f02);
            a10 = fmaf(fmaf(Fr0, sfac, db0 * (1.0f - Fr0)), t0, a10);
            a11 = fmaf(fmaf(Fr1, sfac, db1 * (1.0f - Fr1)), t1, a11);
            a12 = fmaf(fmaf(Fr2, sfac, db2 * (1.0f - Fr2)), t2, a12);
        }
    }

    // ---- wave64 butterfly reduction (6 accumulators) ----
    #pragma unroll
    for (int off = 32; off >= 1; off >>= 1) {
        a00 += __shfl_down(a00, off, 64);
        a01 += __shfl_down(a01, off, 64);
        a02 += __shfl_down(a02, off, 64);
        a10 += __shfl_down(a10, off, 64);
        a11 += __shfl_down(a11, off, 64);
        a12 += __shfl_down(a12, off, 64);
    }

    if (lane == 0) {
        float* o = out + (size_t)n * 6;
        o[0] = a00; o[1] = a01; o[2] = a02;
        o[3] = a10; o[4] = a11; o[5] = a12;
    }
}

extern "C" void kernel_launch(void* const* d_in, const int* in_sizes, int n_in,
                              void* d_out, int out_size, void* d_ws, size_t ws_size,
                              hipStream_t stream) {
    const float* normals  = (const float*)d_in[0];
    const float* albedo   = (const float*)d_in[1];
    const float* metallic = (const float*)d_in[2];
    const float* smooth   = (const float*)d_in[3];
    const float* vdirs    = (const float*)d_in[4];
    const float* env_vis  = (const float*)d_in[5];
    const float* env_map  = (const float*)d_in[6];
    float* out = (float*)d_out;

    const int N = in_sizes[0] / 3;       // 4096 points
    const int blocks = (N + 3) / 4;      // one wave per point, 4 waves/block

    hdr_render_kernel<<<blocks, 256, 0, stream>>>(
        normals, albedo, metallic, smooth, vdirs, env_vis, env_map, out, N);
}